// Round 3
// baseline (29.133 us; speedup 1.0000x reference)
//
#include <hip/hip_runtime.h>

#define TN 6
#define CFC 256
#define HFC 32
#define WFC 88
#define HWC (HFC * WFC)   // 2816
#define EPSF 1e-5f
#define OUTC (3 + CFC)    // 259

typedef _Float16 half8 __attribute__((ext_vector_type(8)));
typedef _Float16 half2t __attribute__((ext_vector_type(2)));

// -------- transpose+convert (6,256,32,88) f32 -> (6,32,88,256) f16 --------
__global__ __launch_bounds__(256) void proj_transpose_f16_kernel(
    const float* __restrict__ src, _Float16* __restrict__ dst)
{
    __shared__ float tile[64][33];
    const int n   = blockIdx.z;
    const int hw0 = blockIdx.x * 32;   // 88 tiles over 2816
    const int c0  = blockIdx.y * 64;   // 4 tiles over 256
    const int tx  = threadIdx.x, ty = threadIdx.y;  // (32, 8)
    const float*  s = src + (size_t)n * (CFC * HWC);
    _Float16*     d = dst + (size_t)n * (CFC * HWC);

#pragma unroll
    for (int kk = 0; kk < 8; ++kk) {
        const int c_l = ty + 8 * kk;
        tile[c_l][tx] = s[(size_t)(c0 + c_l) * HWC + hw0 + tx];
    }
    __syncthreads();

    const int tid   = ty * 32 + tx;
    const int cpair = tid & 31;        // 32 channel-pairs -> 64 channels
    const int hwb   = tid >> 5;        // 8 hw rows per pass
#pragma unroll
    for (int pass = 0; pass < 4; ++pass) {
        const int hw_l = hwb + 8 * pass;
        const int c_l  = cpair * 2;
        half2t hv;
        hv.x = (_Float16)tile[c_l][hw_l];
        hv.y = (_Float16)tile[c_l + 1][hw_l];
        *(half2t*)(d + (size_t)(hw0 + hw_l) * CFC + c0 + c_l) = hv;
    }
}

// ---------------- fused kernel: ONE WAVE per output cell ----------------
// Phase A: lanes 0..11 compute per-(point,camera) projections; valid slots
// compacted into LDS. Phase B (TR): half-wave per texel row, half8 loads.
template <bool TR>
__global__ __launch_bounds__(64) void proj_fuse_kernel(
    const float* __restrict__ points,
    const _Float16* __restrict__ feat16,
    const float* __restrict__ feat32,
    const float* __restrict__ lid2img,
    const float* __restrict__ ego2lid,
    const float* __restrict__ img2lid,
    const int*   __restrict__ img_h,
    const int*   __restrict__ img_w,
    float* __restrict__ out)
{
    __shared__ int    sOff[16];
    __shared__ float4 sW[16];
    __shared__ float  sBack[12][4];

    const int t    = threadIdx.x;   // 0..63
    const int cell = blockIdx.x;    // 0..16383

    // ---- Phase A ----
    bool  valid = false;
    int   off   = 0;
    float w00 = 0.f, w01 = 0.f, w10 = 0.f, w11 = 0.f;
    float bk[4] = {0.f, 0.f, 0.f, 0.f};

    if (t < 12) {
        const int cp = t / 6, n = t % 6;
        const float px = points[cell * 6 + cp * 3 + 0];
        const float py = points[cell * 6 + cp * 3 + 1];
        const float pz = points[cell * 6 + cp * 3 + 2];

        float pr[4];
#pragma unroll
        for (int r = 0; r < 4; ++r) {
            float m0 = 0.f, m1 = 0.f, m2 = 0.f, m3 = 0.f;
#pragma unroll
            for (int k = 0; k < 4; ++k) {
                const float l = lid2img[n * 16 + r * 4 + k];
                m0 += l * ego2lid[n * 16 + k * 4 + 0];
                m1 += l * ego2lid[n * 16 + k * 4 + 1];
                m2 += l * ego2lid[n * 16 + k * 4 + 2];
                m3 += l * ego2lid[n * 16 + k * 4 + 3];
            }
            pr[r] = m0 * px + m1 * py + m2 * pz + m3;
        }

        const float depth  = pr[2];
        const float dmax   = fmaxf(depth, EPSF);
        const float wscale = (float)WFC / (float)img_w[0];
        const float hscale = (float)HFC / (float)img_h[0];
        const float u = pr[0] / dmax * wscale;
        const float v = pr[1] / dmax * hscale;
        valid = (depth > EPSF) && (u >= 0.f) && (u <= (float)(WFC - 1)) &&
                (v >= 0.f) && (v <= (float)(HFC - 1));
        if (valid) {
            const float fx0 = fminf(fmaxf(floorf(u), 0.f), (float)(WFC - 2));
            const float fy0 = fminf(fmaxf(floorf(v), 0.f), (float)(HFC - 2));
            const int   x0  = (int)fx0, y0 = (int)fy0;
            const float wx  = fminf(fmaxf(u - fx0, 0.f), 1.f);
            const float wy  = fminf(fmaxf(v - fy0, 0.f), 1.f);
            w00 = (1.f - wy) * (1.f - wx);
            w01 = (1.f - wy) * wx;
            w10 = wy * (1.f - wx);
            w11 = wy * wx;
            if (TR)
                off = ((n * HFC + y0) * WFC + x0) * CFC;   // f16 element index
            else
                off = n * CFC * HWC + y0 * WFC + x0;       // f32, + ch*HWC later
#pragma unroll
            for (int r = 0; r < 4; ++r)
                bk[r] = img2lid[n * 16 + r * 4 + 0] * pr[0] +
                        img2lid[n * 16 + r * 4 + 1] * pr[1] +
                        img2lid[n * 16 + r * 4 + 2] * pr[2] +
                        img2lid[n * 16 + r * 4 + 3] * pr[3];
        }
    }

    const unsigned long long m = __ballot(valid);
    const int cnt0 = __popcll(m & 0x03Full);
    const int cnt1 = __popcll(m & 0xFC0ull);

    if (valid) {
        const int   pos = __popcll(m & ((1ull << t) - 1ull));
        const float scl = 0.5f / fmaxf((float)(t < 6 ? cnt0 : cnt1), 1.f);
        sOff[pos] = off;
        sW[pos]   = make_float4(w00 * scl, w01 * scl, w10 * scl, w11 * scl);
    }
    if (t < 12) {
        sBack[t][0] = bk[0]; sBack[t][1] = bk[1];
        sBack[t][2] = bk[2]; sBack[t][3] = bk[3];
    }
    __syncthreads();

    // ---- xyz (lane 0) ----
    if (t == 0) {
        float xyz[3] = {0.f, 0.f, 0.f};
#pragma unroll
        for (int cp = 0; cp < 2; ++cp) {
            const float cntf = fmaxf((float)(cp == 0 ? cnt0 : cnt1), 1.f);
            float b[4];
#pragma unroll
            for (int r = 0; r < 4; ++r) {
                float s = 0.f;
#pragma unroll
                for (int n = 0; n < TN; ++n) s += sBack[cp * 6 + n][r];
                b[r] = s / cntf;
            }
            const float wv = b[3];
            const float dw = (fabsf(wv) < EPSF) ? 1.f : wv;
#pragma unroll
            for (int r = 0; r < 3; ++r) xyz[r] += b[r] / dw;
        }
        float* op = out + (size_t)cell * OUTC;
        op[0] = xyz[0] * 0.5f; op[1] = xyz[1] * 0.5f; op[2] = xyz[2] * 0.5f;
    }

    const int V = (int)__popcll(m);

    if (TR) {
        // half-wave h=0 -> (f00,f01); h=1 -> (f10,f11). 8 channels/lane.
        const int h  = t >> 5;
        const int cg = t & 31;
        float acc[8] = {0.f, 0.f, 0.f, 0.f, 0.f, 0.f, 0.f, 0.f};

        for (int s = 0; s < V; ++s) {
            const int    o = sOff[s];
            const float4 w = sW[s];
            const float wa = h ? w.z : w.x;
            const float wb = h ? w.w : w.y;
            const _Float16* bp = feat16 + (size_t)o + (size_t)h * (WFC * CFC) + cg * 8;
            const half8 fL = *(const half8*)bp;
            const half8 fR = *(const half8*)(bp + CFC);
#pragma unroll
            for (int j = 0; j < 8; ++j)
                acc[j] += wa * (float)fL[j] + wb * (float)fR[j];
        }
#pragma unroll
        for (int j = 0; j < 8; ++j)
            acc[j] += __shfl(acc[j], t ^ 32, 64);

        if (t < 32) {
            float* op = out + (size_t)cell * OUTC + 3 + cg * 8;
#pragma unroll
            for (int j = 0; j < 8; ++j) op[j] = acc[j];
        }
    } else {
        // fallback: original f32 layout, 4 channels/lane, scalar gathers
        float a0 = 0.f, a1 = 0.f, a2 = 0.f, a3 = 0.f;
        for (int s = 0; s < V; ++s) {
            const int    o = sOff[s];
            const float4 w = sW[s];
#pragma unroll
            for (int c = 0; c < 4; ++c) {
                const float* bp = feat32 + (size_t)o + (size_t)(4 * t + c) * HWC;
                const float f00 = bp[0];
                const float f01 = bp[1];
                const float f10 = bp[WFC];
                const float f11 = bp[WFC + 1];
                const float r = w.x * f00 + w.y * f01 + w.z * f10 + w.w * f11;
                if (c == 0) a0 += r; else if (c == 1) a1 += r;
                else if (c == 2) a2 += r; else a3 += r;
            }
        }
        float* op = out + (size_t)cell * OUTC + 3 + t * 4;
        op[0] = a0; op[1] = a1; op[2] = a2; op[3] = a3;
    }
}

extern "C" void kernel_launch(void* const* d_in, const int* in_sizes, int n_in,
                              void* d_out, int out_size, void* d_ws, size_t ws_size,
                              hipStream_t stream)
{
    const float* points   = (const float*)d_in[0];
    const float* img_feat = (const float*)d_in[1];
    const float* lid2img  = (const float*)d_in[2];
    const float* ego2lid  = (const float*)d_in[3];
    const float* img2lid  = (const float*)d_in[4];
    const int*   img_h    = (const int*)d_in[5];
    const int*   img_w    = (const int*)d_in[6];
    float*       out      = (float*)d_out;

    const size_t need  = (size_t)TN * CFC * HWC * sizeof(_Float16);  // 8.65 MB
    const int    ncell = 128 * 128;

    if (ws_size >= need) {
        _Float16* featT = (_Float16*)d_ws;
        dim3 tg(HWC / 32, CFC / 64, TN);  // (88, 4, 6)
        proj_transpose_f16_kernel<<<tg, dim3(32, 8), 0, stream>>>(img_feat, featT);
        proj_fuse_kernel<true><<<ncell, 64, 0, stream>>>(
            points, featT, (const float*)nullptr,
            lid2img, ego2lid, img2lid, img_h, img_w, out);
    } else {
        proj_fuse_kernel<false><<<ncell, 64, 0, stream>>>(
            points, (const _Float16*)nullptr, img_feat,
            lid2img, ego2lid, img2lid, img_h, img_w, out);
    }
}

// Round 4
// 22.431 us; speedup vs baseline: 1.2988x; 1.2988x over previous
//
#include <hip/hip_runtime.h>

#define TN 6
#define CFC 256
#define HFC 32
#define WFC 88
#define HWC (HFC * WFC)   // 2816
#define EPSF 1e-5f
#define OUTC (3 + CFC)    // 259

typedef _Float16 half8  __attribute__((ext_vector_type(8)));
typedef _Float16 half2t __attribute__((ext_vector_type(2)));
typedef float    f4u    __attribute__((ext_vector_type(4), aligned(4)));

// -------- transpose+convert (6,256,32,88) f32 -> (6,32,88,256) f16 --------
__global__ __launch_bounds__(256) void proj_transpose_f16_kernel(
    const float* __restrict__ src, _Float16* __restrict__ dst)
{
    __shared__ float tile[64][33];
    const int n   = blockIdx.z;
    const int hw0 = blockIdx.x * 32;
    const int c0  = blockIdx.y * 64;
    const int tx  = threadIdx.x, ty = threadIdx.y;  // (32, 8)
    const float*  s = src + (size_t)n * (CFC * HWC);
    _Float16*     d = dst + (size_t)n * (CFC * HWC);

#pragma unroll
    for (int kk = 0; kk < 8; ++kk) {
        const int c_l = ty + 8 * kk;
        tile[c_l][tx] = s[(size_t)(c0 + c_l) * HWC + hw0 + tx];
    }
    __syncthreads();

    const int tid   = ty * 32 + tx;
    const int cpair = tid & 31;
    const int hwb   = tid >> 5;
#pragma unroll
    for (int pass = 0; pass < 4; ++pass) {
        const int hw_l = hwb + 8 * pass;
        const int c_l  = cpair * 2;
        half2t hv;
        hv.x = (_Float16)tile[c_l][hw_l];
        hv.y = (_Float16)tile[c_l + 1][hw_l];
        *(half2t*)(d + (size_t)(hw0 + hw_l) * CFC + c0 + c_l) = hv;
    }
}

// ---------------- fused kernel: ONE WAVE handles FOUR cells ----------------
// Lane layout: cell_local = t>>4 (4 cells/wave); sub = t&15;
// cp = sub>>3; sl = sub&7 (slots 0..5 active, 6..7 pad).
// No LDS, no barriers: ballot + shfl only.
__global__ __launch_bounds__(64) void proj_fuse4_kernel(
    const float* __restrict__ points,
    const _Float16* __restrict__ feat,
    const float* __restrict__ lid2img,
    const float* __restrict__ ego2lid,
    const float* __restrict__ img2lid,
    const int*   __restrict__ img_h,
    const int*   __restrict__ img_w,
    float* __restrict__ out)
{
    const int t     = threadIdx.x;
    const int c_loc = t >> 4;
    const int sub   = t & 15;
    const int cp    = sub >> 3;
    const int sl    = sub & 7;
    const int cell  = blockIdx.x * 4 + c_loc;

    // ---- Phase A: per-slot projection ----
    bool  valid = false;
    int   off   = 0;
    float w00 = 0.f, w01 = 0.f, w10 = 0.f, w11 = 0.f;
    float bk0 = 0.f, bk1 = 0.f, bk2 = 0.f, bk3 = 0.f;

    if (sl < 6) {
        const int n = sl;
        const float px = points[cell * 6 + cp * 3 + 0];
        const float py = points[cell * 6 + cp * 3 + 1];
        const float pz = points[cell * 6 + cp * 3 + 2];

        float pr[4];
#pragma unroll
        for (int r = 0; r < 4; ++r) {
            float m0 = 0.f, m1 = 0.f, m2 = 0.f, m3 = 0.f;
#pragma unroll
            for (int k = 0; k < 4; ++k) {
                const float l = lid2img[n * 16 + r * 4 + k];
                m0 += l * ego2lid[n * 16 + k * 4 + 0];
                m1 += l * ego2lid[n * 16 + k * 4 + 1];
                m2 += l * ego2lid[n * 16 + k * 4 + 2];
                m3 += l * ego2lid[n * 16 + k * 4 + 3];
            }
            pr[r] = m0 * px + m1 * py + m2 * pz + m3;
        }

        const float depth  = pr[2];
        const float dmax   = fmaxf(depth, EPSF);
        const float wscale = (float)WFC / (float)img_w[0];
        const float hscale = (float)HFC / (float)img_h[0];
        const float u = pr[0] / dmax * wscale;
        const float v = pr[1] / dmax * hscale;
        valid = (depth > EPSF) && (u >= 0.f) && (u <= (float)(WFC - 1)) &&
                (v >= 0.f) && (v <= (float)(HFC - 1));
        if (valid) {
            const float fx0 = fminf(fmaxf(floorf(u), 0.f), (float)(WFC - 2));
            const float fy0 = fminf(fmaxf(floorf(v), 0.f), (float)(HFC - 2));
            const int   x0  = (int)fx0, y0 = (int)fy0;
            const float wx  = fminf(fmaxf(u - fx0, 0.f), 1.f);
            const float wy  = fminf(fmaxf(v - fy0, 0.f), 1.f);
            w00 = (1.f - wy) * (1.f - wx);
            w01 = (1.f - wy) * wx;
            w10 = wy * (1.f - wx);
            w11 = wy * wx;
            off = ((n * HFC + y0) * WFC + x0) * CFC;  // f16 element index
#pragma unroll
            for (int r = 0; r < 4; ++r) {
                const float b = img2lid[n * 16 + r * 4 + 0] * pr[0] +
                                img2lid[n * 16 + r * 4 + 1] * pr[1] +
                                img2lid[n * 16 + r * 4 + 2] * pr[2] +
                                img2lid[n * 16 + r * 4 + 3] * pr[3];
                if (r == 0) bk0 = b; else if (r == 1) bk1 = b;
                else if (r == 2) bk2 = b; else bk3 = b;
            }
        }
    }

    const unsigned long long m = __ballot(valid);
    const int base = c_loc * 16;
    const int cnt0 = __popcll((m >> base) & 0x3Full);
    const int cnt1 = __popcll((m >> (base + 8)) & 0x3Full);

    // pre-scale bilerp weights by 0.5 / cnt(point)
    {
        const float scl = 0.5f / fmaxf((float)(cp == 0 ? cnt0 : cnt1), 1.f);
        w00 *= scl; w01 *= scl; w10 *= scl; w11 *= scl;
    }

    // ---- back-projection reduce within each aligned 8-lane cp-group ----
#pragma unroll
    for (int d = 1; d < 8; d <<= 1) {
        bk0 += __shfl_xor(bk0, d);
        bk1 += __shfl_xor(bk1, d);
        bk2 += __shfl_xor(bk2, d);
        bk3 += __shfl_xor(bk3, d);
    }
    // pull cp=1 group sums into every lane of the cell
    const int  gl1 = (t & ~15) | 8;
    const float g0 = __shfl(bk0, gl1);
    const float g1 = __shfl(bk1, gl1);
    const float g2 = __shfl(bk2, gl1);
    const float g3 = __shfl(bk3, gl1);

    if (sub == 0) {
        float xyz[3] = {0.f, 0.f, 0.f};
        {
            const float cf = fmaxf((float)cnt0, 1.f);
            const float b3 = bk3 / cf;
            const float dw = (fabsf(b3) < EPSF) ? 1.f : b3;
            xyz[0] += (bk0 / cf) / dw;
            xyz[1] += (bk1 / cf) / dw;
            xyz[2] += (bk2 / cf) / dw;
        }
        {
            const float cf = fmaxf((float)cnt1, 1.f);
            const float b3 = g3 / cf;
            const float dw = (fabsf(b3) < EPSF) ? 1.f : b3;
            xyz[0] += (g0 / cf) / dw;
            xyz[1] += (g1 / cf) / dw;
            xyz[2] += (g2 / cf) / dw;
        }
        float* op = out + (size_t)cell * OUTC;
        op[0] = xyz[0] * 0.5f; op[1] = xyz[1] * 0.5f; op[2] = xyz[2] * 0.5f;
    }

    // ---- Phase B: gather, 4 cells per wave ----
    const int h  = t >> 5;    // 0: (f00,f01) row, 1: (f10,f11) row
    const int cg = t & 31;    // 8 channels per lane
    float acc[4][8];
#pragma unroll
    for (int c = 0; c < 4; ++c)
#pragma unroll
        for (int j = 0; j < 8; ++j) acc[c][j] = 0.f;

#pragma unroll
    for (int c = 0; c < 4; ++c) {
#pragma unroll
        for (int g = 0; g < 2; ++g) {
            const unsigned mask6 = (unsigned)(m >> (c * 16 + g * 8)) & 0x3Fu;
#pragma unroll
            for (int s2 = 0; s2 < 6; ++s2) {
                if (mask6 & (1u << s2)) {
                    const int src = c * 16 + g * 8 + s2;
                    const int   o   = __shfl(off, src);
                    const float a00 = __shfl(w00, src);
                    const float a01 = __shfl(w01, src);
                    const float a10 = __shfl(w10, src);
                    const float a11 = __shfl(w11, src);
                    const float wa = h ? a10 : a00;
                    const float wb = h ? a11 : a01;
                    const _Float16* bp = feat + (size_t)o +
                                         (size_t)h * (WFC * CFC) + cg * 8;
                    const half8 fL = *(const half8*)bp;
                    const half8 fR = *(const half8*)(bp + CFC);
#pragma unroll
                    for (int j = 0; j < 8; ++j)
                        acc[c][j] += wa * (float)fL[j] + wb * (float)fR[j];
                }
            }
        }
    }

#pragma unroll
    for (int c = 0; c < 4; ++c) {
#pragma unroll
        for (int j = 0; j < 8; ++j)
            acc[c][j] += __shfl_xor(acc[c][j], 32);
        const int cell_c = blockIdx.x * 4 + c;
        float* op = out + (size_t)cell_c * OUTC + 3 + cg * 8 + h * 4;
        f4u v;
#pragma unroll
        for (int j = 0; j < 4; ++j)
            v[j] = h ? acc[c][4 + j] : acc[c][j];
        *(f4u*)op = v;
    }
}

// ---------------- fallback (no workspace): original f32 layout ----------------
__global__ __launch_bounds__(64) void proj_fuse_cell_f32_kernel(
    const float* __restrict__ points,
    const float* __restrict__ feat32,
    const float* __restrict__ lid2img,
    const float* __restrict__ ego2lid,
    const float* __restrict__ img2lid,
    const int*   __restrict__ img_h,
    const int*   __restrict__ img_w,
    float* __restrict__ out)
{
    __shared__ int    sOff[16];
    __shared__ float4 sW[16];
    __shared__ float  sBack[12][4];

    const int t    = threadIdx.x;
    const int cell = blockIdx.x;

    bool  valid = false;
    int   off   = 0;
    float w00 = 0.f, w01 = 0.f, w10 = 0.f, w11 = 0.f;
    float bk[4] = {0.f, 0.f, 0.f, 0.f};

    if (t < 12) {
        const int cp = t / 6, n = t % 6;
        const float px = points[cell * 6 + cp * 3 + 0];
        const float py = points[cell * 6 + cp * 3 + 1];
        const float pz = points[cell * 6 + cp * 3 + 2];
        float pr[4];
#pragma unroll
        for (int r = 0; r < 4; ++r) {
            float m0 = 0.f, m1 = 0.f, m2 = 0.f, m3 = 0.f;
#pragma unroll
            for (int k = 0; k < 4; ++k) {
                const float l = lid2img[n * 16 + r * 4 + k];
                m0 += l * ego2lid[n * 16 + k * 4 + 0];
                m1 += l * ego2lid[n * 16 + k * 4 + 1];
                m2 += l * ego2lid[n * 16 + k * 4 + 2];
                m3 += l * ego2lid[n * 16 + k * 4 + 3];
            }
            pr[r] = m0 * px + m1 * py + m2 * pz + m3;
        }
        const float depth  = pr[2];
        const float dmax   = fmaxf(depth, EPSF);
        const float u = pr[0] / dmax * ((float)WFC / (float)img_w[0]);
        const float v = pr[1] / dmax * ((float)HFC / (float)img_h[0]);
        valid = (depth > EPSF) && (u >= 0.f) && (u <= (float)(WFC - 1)) &&
                (v >= 0.f) && (v <= (float)(HFC - 1));
        if (valid) {
            const float fx0 = fminf(fmaxf(floorf(u), 0.f), (float)(WFC - 2));
            const float fy0 = fminf(fmaxf(floorf(v), 0.f), (float)(HFC - 2));
            const int   x0  = (int)fx0, y0 = (int)fy0;
            const float wx  = fminf(fmaxf(u - fx0, 0.f), 1.f);
            const float wy  = fminf(fmaxf(v - fy0, 0.f), 1.f);
            w00 = (1.f - wy) * (1.f - wx); w01 = (1.f - wy) * wx;
            w10 = wy * (1.f - wx);         w11 = wy * wx;
            off = n * CFC * HWC + y0 * WFC + x0;
#pragma unroll
            for (int r = 0; r < 4; ++r)
                bk[r] = img2lid[n * 16 + r * 4 + 0] * pr[0] +
                        img2lid[n * 16 + r * 4 + 1] * pr[1] +
                        img2lid[n * 16 + r * 4 + 2] * pr[2] +
                        img2lid[n * 16 + r * 4 + 3] * pr[3];
        }
    }

    const unsigned long long m = __ballot(valid);
    const int cnt0 = __popcll(m & 0x03Full);
    const int cnt1 = __popcll(m & 0xFC0ull);

    if (valid) {
        const int   pos = __popcll(m & ((1ull << t) - 1ull));
        const float scl = 0.5f / fmaxf((float)(t < 6 ? cnt0 : cnt1), 1.f);
        sOff[pos] = off;
        sW[pos]   = make_float4(w00 * scl, w01 * scl, w10 * scl, w11 * scl);
    }
    if (t < 12) {
        sBack[t][0] = bk[0]; sBack[t][1] = bk[1];
        sBack[t][2] = bk[2]; sBack[t][3] = bk[3];
    }
    __syncthreads();

    if (t == 0) {
        float xyz[3] = {0.f, 0.f, 0.f};
#pragma unroll
        for (int cpp = 0; cpp < 2; ++cpp) {
            const float cntf = fmaxf((float)(cpp == 0 ? cnt0 : cnt1), 1.f);
            float b[4];
#pragma unroll
            for (int r = 0; r < 4; ++r) {
                float s = 0.f;
#pragma unroll
                for (int n = 0; n < TN; ++n) s += sBack[cpp * 6 + n][r];
                b[r] = s / cntf;
            }
            const float wv = b[3];
            const float dw = (fabsf(wv) < EPSF) ? 1.f : wv;
#pragma unroll
            for (int r = 0; r < 3; ++r) xyz[r] += b[r] / dw;
        }
        float* op = out + (size_t)cell * OUTC;
        op[0] = xyz[0] * 0.5f; op[1] = xyz[1] * 0.5f; op[2] = xyz[2] * 0.5f;
    }

    const int V = (int)__popcll(m);
    float a0 = 0.f, a1 = 0.f, a2 = 0.f, a3 = 0.f;
    for (int s = 0; s < V; ++s) {
        const int    o = sOff[s];
        const float4 w = sW[s];
#pragma unroll
        for (int c = 0; c < 4; ++c) {
            const float* bp = feat32 + (size_t)o + (size_t)(4 * t + c) * HWC;
            const float f00 = bp[0];
            const float f01 = bp[1];
            const float f10 = bp[WFC];
            const float f11 = bp[WFC + 1];
            const float r = w.x * f00 + w.y * f01 + w.z * f10 + w.w * f11;
            if (c == 0) a0 += r; else if (c == 1) a1 += r;
            else if (c == 2) a2 += r; else a3 += r;
        }
    }
    float* op = out + (size_t)cell * OUTC + 3 + t * 4;
    op[0] = a0; op[1] = a1; op[2] = a2; op[3] = a3;
}

extern "C" void kernel_launch(void* const* d_in, const int* in_sizes, int n_in,
                              void* d_out, int out_size, void* d_ws, size_t ws_size,
                              hipStream_t stream)
{
    const float* points   = (const float*)d_in[0];
    const float* img_feat = (const float*)d_in[1];
    const float* lid2img  = (const float*)d_in[2];
    const float* ego2lid  = (const float*)d_in[3];
    const float* img2lid  = (const float*)d_in[4];
    const int*   img_h    = (const int*)d_in[5];
    const int*   img_w    = (const int*)d_in[6];
    float*       out      = (float*)d_out;

    const size_t need  = (size_t)TN * CFC * HWC * sizeof(_Float16);  // 8.65 MB
    const int    ncell = 128 * 128;

    if (ws_size >= need) {
        _Float16* featT = (_Float16*)d_ws;
        dim3 tg(HWC / 32, CFC / 64, TN);  // (88, 4, 6)
        proj_transpose_f16_kernel<<<tg, dim3(32, 8), 0, stream>>>(img_feat, featT);
        proj_fuse4_kernel<<<ncell / 4, 64, 0, stream>>>(
            points, featT, lid2img, ego2lid, img2lid, img_h, img_w, out);
    } else {
        proj_fuse_cell_f32_kernel<<<ncell, 64, 0, stream>>>(
            points, img_feat, lid2img, ego2lid, img2lid, img_h, img_w, out);
    }
}